// Round 12
// baseline (117.267 us; speedup 1.0000x reference)
//
#include <hip/hip_runtime.h>
#include <hip/hip_bf16.h>
#include <hip/hip_fp16.h>

typedef __attribute__((ext_vector_type(8))) _Float16 half8;
typedef __attribute__((ext_vector_type(2))) _Float16 f16x2;
typedef __attribute__((ext_vector_type(8))) short short8;
typedef __attribute__((ext_vector_type(4))) float f32x4;

#define C_ 128
#define XJ_OFF 33554432

__device__ __forceinline__ unsigned short f2h(float f) {
    return __builtin_bit_cast(unsigned short, (_Float16)f);
}
__device__ __forceinline__ f16x2 pkrtz(float x, float y) {
    return __builtin_bit_cast(f16x2, __builtin_amdgcn_cvt_pkrtz(x, y));
}
__device__ __forceinline__ float prelu_f(float x, float s) {
    return fmaxf(x, 0.f) + s * fminf(x, 0.f);
}
__device__ __forceinline__ half8 prelu_h8(half8 x, half8 sl) {
    half8 z = {0, 0, 0, 0, 0, 0, 0, 0};
    half8 mx = __builtin_elementwise_max(x, z);
    half8 mn = __builtin_elementwise_min(x, z);
    return mn * sl + mx;
}

// ---- K0: convert + transpose weights to f16 in d_ws ----
__global__ __launch_bounds__(256) void prep_weights(
    const float* __restrict__ Wm1, const float* __restrict__ Wm2,
    const float* __restrict__ Wg1a, const float* __restrict__ Wg2a,
    short* __restrict__ ws)
{
    int id = blockIdx.x * 256 + threadIdx.x;
    if (id < 8192) {
        int c = id >> 5, kb = (id & 31) * 8;
        short8 v;
        #pragma unroll
        for (int e = 0; e < 8; ++e) v[e] = (short)f2h(Wm1[(kb + e) * 256 + c]);
        *(short8*)(ws + c * 256 + kb) = v;
    }
    if (id < 4096) {
        int c = id >> 5, kb = (id & 31) * 8;
        short8 a, b, d;
        #pragma unroll
        for (int e = 0; e < 8; ++e) {
            a[e] = (short)f2h(Wm2 [(kb + e) * C_ + c]);
            b[e] = (short)f2h(Wg1a[(kb + e) * C_ + c]);
            d[e] = (short)f2h(Wg2a[(kb + e) * C_ + c]);
        }
        *(short8*)(ws + 65536  + c * 256 + kb) = a;
        *(short8*)(ws + 98304  + c * 256 + kb) = b;
        *(short8*)(ws + 131072 + c * 256 + kb) = d;
    }
}

// ---- K1: per-graph compute + 32KB staging. 256 blocks x 512 threads. ----
// Compute waves 0-3: P4 U/V + P5 pair MFMA + logit.
// Store waves 4-7: ug/cbias, then stage x1g -> xi j=0 rows, x2g -> xj i=0
// tile, and exit.
__global__ __launch_bounds__(512, 1) void interactions_core(
    const float* __restrict__ x1_, const float* __restrict__ x2_,
    const float* __restrict__ inter, const float* __restrict__ aP,
    const short* __restrict__ Wt,
    const float* __restrict__ bm1, const float* __restrict__ bm2,
    const float* __restrict__ Wm3, const float* __restrict__ bm3,
    const float* __restrict__ pm0p, const float* __restrict__ pm1p,
    const float* __restrict__ pm2p,
    const float* __restrict__ bg1a, const float* __restrict__ Wg1b,
    const float* __restrict__ bg1b, const float* __restrict__ pw1p,
    const float* __restrict__ bg2a, const float* __restrict__ Wg2b,
    const float* __restrict__ bg2b, const float* __restrict__ pw2p,
    float* __restrict__ out)
{
    __shared__ __align__(16) float xs1[32 * 132];
    __shared__ __align__(16) float xs2[32 * 132];
    __shared__ __align__(16) unsigned char Ub[16384];
    __shared__ __align__(16) unsigned char Vb[16384];
    __shared__ __align__(16) float rr[2][C_];
    __shared__ __align__(16) float tv[C_];
    __shared__ __align__(16) float ugs[C_];
    __shared__ float wgtp[2][2][32];
    __shared__ float red[4];
    __shared__ float cbias_s;
    __shared__ int cnt1, cnt2;

    const int t = threadIdx.x;
    const int g = blockIdx.x;
    const int lane = t & 63;
    const int w = t >> 6;

    if (t == 0) { cnt1 = 0; cnt2 = 0; }

    // P0
    {
        const float* s1 = x1_ + (size_t)g * 4096;
        const float* s2 = x2_ + (size_t)g * 4096;
        #pragma unroll
        for (int q = 0; q < 2; ++q) {
            int idx = q * 512 + t;
            int row = idx >> 5, cc = (idx & 31) * 4;
            *(f32x4*)(xs1 + row * 132 + cc) = *(const f32x4*)(s1 + idx * 4);
            *(f32x4*)(xs2 + row * 132 + cc) = *(const f32x4*)(s2 + idx * 4);
        }
    }
    __syncthreads();

    // P1
    if (t < 128) {
        float s = 0.f;
        for (int n = 0; n < 32; ++n) s += xs1[n * 132 + t];
        rr[0][t] = s;
    } else if (t < 256) {
        int c = t - 128;
        float s = 0.f;
        for (int n = 0; n < 32; ++n) s += xs2[n * 132 + c];
        rr[1][c] = s;
    } else if (t < 384) {
        int c = t - 256;
        tv[c] = aP[c] * inter[(size_t)g * C_ + c];
    }
    __syncthreads();

    // P2: gating (8 waves: 4 tasks x 2 halves)
    {
        const int task = w & 3;
        const int half = w >> 2;
        const int sd = task >> 1;
        const int rt = task & 1;
        const float* xs = sd ? xs2 : xs1;
        const float* roth = sd ? rr[0] : rr[1];
        const short* WgT = Wt + (sd ? 131072 : 98304);
        const float* bga = sd ? bg2a : bg1a;
        const float* wgb = sd ? Wg2b : Wg1b;
        const float pw  = sd ? pw2p[0] : pw1p[0];
        const int row = rt * 16 + (lane & 15);
        const int kg = (lane >> 4) * 8;

        half8 afr[8];
        #pragma unroll
        for (int kt = 0; kt < 8; ++kt) {
            const float* p = (kt < 4) ? (xs + row * 132 + kt * 32 + kg)
                                      : (roth + (kt - 4) * 32 + kg);
            f32x4 lo = *(const f32x4*)p;
            f32x4 hi = *(const f32x4*)(p + 4);
            f16x2 a = pkrtz(lo[0], lo[1]);
            f16x2 b = pkrtz(lo[2], lo[3]);
            f16x2 c = pkrtz(hi[0], hi[1]);
            f16x2 d = pkrtz(hi[2], hi[3]);
            half8 fr = {a[0], a[1], b[0], b[1], c[0], c[1], d[0], d[1]};
            afr[kt] = fr;
        }
        float pr[4] = {0, 0, 0, 0};
        #pragma unroll
        for (int cq = 0; cq < 4; ++cq) {
            const int ct = half * 4 + cq;
            const int c = ct * 16 + (lane & 15);
            const short* wp = WgT + c * 256 + kg;
            f32x4 acc = {0, 0, 0, 0};
            #pragma unroll
            for (int kt = 0; kt < 8; ++kt)
                acc = __builtin_amdgcn_mfma_f32_16x16x32_f16(
                          afr[kt], *(const half8*)(wp + kt * 32), acc, 0, 0, 0);
            const float bgac = bga[c], wgbc = wgb[c];
            #pragma unroll
            for (int r = 0; r < 4; ++r)
                pr[r] += prelu_f(acc[r] + bgac, pw) * wgbc;
        }
        #pragma unroll
        for (int r = 0; r < 4; ++r) {
            float p = pr[r];
            p += __shfl_xor(p, 1); p += __shfl_xor(p, 2);
            p += __shfl_xor(p, 4); p += __shfl_xor(p, 8);
            if ((lane & 15) == 0)
                wgtp[half][sd][rt * 16 + (lane >> 4) * 4 + r] = p;
        }
    }
    __syncthreads();

    // P3: sigmoid + scale xs in place
    {
        const float bgb1 = bg1b[0], bgb2 = bg2b[0];
        const int cc = (t & 31) * 4;
        const int tn = t >> 5;
        #pragma unroll
        for (int m = 0; m < 2; ++m) {
            const int nr = m * 16 + tn;
            const float w1v = 1.f / (1.f + __expf(-(wgtp[0][0][nr] + wgtp[1][0][nr] + bgb1)));
            const float w2v = 1.f / (1.f + __expf(-(wgtp[0][1][nr] + wgtp[1][1][nr] + bgb2)));
            f32x4 v1 = *(f32x4*)(xs1 + nr * 132 + cc);
            f32x4 v2 = *(f32x4*)(xs2 + nr * 132 + cc);
            v1 *= w1v; v2 *= w2v;
            *(f32x4*)(xs1 + nr * 132 + cc) = v1;
            *(f32x4*)(xs2 + nr * 132 + cc) = v2;
        }
    }
    __syncthreads();   // LAST full-block barrier

    float* oxi = out + 256 + (size_t)g * 131072;
    float* oxj = oxi + XJ_OFF;

    if (w >= 4) {
        // ===== STORE WAVES (4-7): ug/cbias, signal, stage 32KB, exit =====
        if (t < 384) {
            const int c = t - 256;
            const float* wr = Wm3 + c * C_;
            float s0 = 0, s1 = 0, s2 = 0, s3 = 0;
            #pragma unroll
            for (int k = 0; k < 128; k += 4) {
                f32x4 wv = *(const f32x4*)(wr + k);
                s0 += wv[0] * tv[k];     s1 += wv[1] * tv[k + 1];
                s2 += wv[2] * tv[k + 2]; s3 += wv[3] * tv[k + 3];
            }
            ugs[c] = (s0 + s1) + (s2 + s3);
        } else if (w == 7) {
            float p = bm3[lane] * tv[lane] + bm3[64 + lane] * tv[64 + lane];
            #pragma unroll
            for (int m = 1; m < 64; m <<= 1) p += __shfl_xor(p, m);
            if (lane == 0) cbias_s = p;
        }
        __threadfence_block();
        if (lane == 0)
            __hip_atomic_fetch_add(&cnt1, 1, __ATOMIC_RELEASE, __HIP_MEMORY_SCOPE_WORKGROUP);

        // staging: waves 4,5 -> x1g rows into xi j=0 slots; 6,7 -> x2g tile
        if (w < 6) {
            const int base = (w - 4) * 512;
            #pragma unroll
            for (int m = 0; m < 8; ++m) {
                const int idx = base + m * 64 + lane;      // float4 idx [0,1024)
                const int row = idx >> 5, c4 = (idx & 31) * 4;
                *(f32x4*)(oxi + (size_t)row * 4096 + c4) =
                    *(const f32x4*)(xs1 + row * 132 + c4);
            }
        } else {
            const int base = (w - 6) * 512;
            #pragma unroll
            for (int m = 0; m < 8; ++m) {
                const int idx = base + m * 64 + lane;
                const int row = idx >> 5, c4 = (idx & 31) * 4;
                *(f32x4*)(oxj + idx * 4) =
                    *(const f32x4*)(xs2 + row * 132 + c4);
            }
        }
    } else {
        // ===== COMPUTE WAVES (0-3) =====
        // P4: U/V via f16 MFMA into Ub/Vb (swizzled)
        {
            const int sd = w >> 1;
            const int rt = w & 1;
            const float* xs = sd ? xs2 : xs1;
            const float pm0 = pm0p[0];
            const int row = rt * 16 + (lane & 15);
            const int kg = (lane >> 4) * 8;
            half8 afr[4];
            #pragma unroll
            for (int kt = 0; kt < 4; ++kt) {
                const float* p = xs + row * 132 + kt * 32 + kg;
                f32x4 lo = *(const f32x4*)p;
                f32x4 hi = *(const f32x4*)(p + 4);
                f16x2 a = pkrtz(prelu_f(lo[0], pm0), prelu_f(lo[1], pm0));
                f16x2 b = pkrtz(prelu_f(lo[2], pm0), prelu_f(lo[3], pm0));
                f16x2 c = pkrtz(prelu_f(hi[0], pm0), prelu_f(hi[1], pm0));
                f16x2 d = pkrtz(prelu_f(hi[2], pm0), prelu_f(hi[3], pm0));
                half8 fr = {a[0], a[1], b[0], b[1], c[0], c[1], d[0], d[1]};
                afr[kt] = fr;
            }
            unsigned char* dst = sd ? Vb : Ub;
            #pragma unroll
            for (int ct = 0; ct < 16; ++ct) {
                const int c = ct * 16 + (lane & 15);
                const short* wp = Wt + c * 256 + sd * 128 + kg;
                f32x4 av = {0, 0, 0, 0};
                #pragma unroll
                for (int kt = 0; kt < 4; ++kt)
                    av = __builtin_amdgcn_mfma_f32_16x16x32_f16(
                             afr[kt], *(const half8*)(wp + kt * 32), av, 0, 0, 0);
                const float badd = sd ? 0.f : bm1[c];
                #pragma unroll
                for (int r = 0; r < 4; ++r) {
                    const int n = rt * 16 + (lane >> 4) * 4 + r;
                    const int off = n * 512 + ((2 * c + ((n & 7) << 6)) & 511);
                    *(unsigned short*)(dst + off) = f2h(av[r] + badd);
                }
            }
        }
        __threadfence_block();
        if (lane == 0)
            __hip_atomic_fetch_add(&cnt1, 1, __ATOMIC_RELEASE, __HIP_MEMORY_SCOPE_WORKGROUP);
        while (__hip_atomic_load(&cnt1, __ATOMIC_ACQUIRE, __HIP_MEMORY_SCOPE_WORKGROUP) < 8)
            __builtin_amdgcn_s_sleep(1);
        __threadfence_block();

        // P5: pair loop
        float psum = 0.f;
        {
            const float pm1v = pm1p[0], pm2v = pm2p[0];
            const _Float16 pm1s = (_Float16)pm1v;
            const half8 pm1h = {pm1s, pm1s, pm1s, pm1s, pm1s, pm1s, pm1s, pm1s};
            const int cl = lane & 15;
            const int kg8 = (lane >> 4) * 8;
            const int kg16 = kg8 * 2;
            const int c0 = (2 * w) * 16 + cl, c1 = (2 * w + 1) * 16 + cl;
            half8 Bf0[8], Bf1[8];
            const short* w2p0 = Wt + 65536 + c0 * 256 + kg8;
            const short* w2p1 = Wt + 65536 + c1 * 256 + kg8;
            #pragma unroll
            for (int kt = 0; kt < 8; ++kt) {
                Bf0[kt] = *(const half8*)(w2p0 + kt * 32);
                Bf1[kt] = *(const half8*)(w2p1 + kt * 32);
            }
            const float bm2c0 = bm2[c0], bm2c1 = bm2[c1];
            const float ug0 = ugs[c0], ug1 = ugs[c1];

            half8 VrA[8], VrB[8];
            {
                const int j0 = cl, j1 = 16 + cl;
                #pragma unroll
                for (int kt = 0; kt < 8; ++kt) {
                    const int koff = kt * 64 + kg16;
                    VrA[kt] = *(const half8*)(Vb + j0 * 512 + ((koff + ((j0 & 7) << 6)) & 511));
                    VrB[kt] = *(const half8*)(Vb + j1 * 512 + ((koff + ((j1 & 7) << 6)) & 511));
                }
            }

            #pragma unroll 2
            for (int i = 0; i < 32; ++i) {
                const int ub = i * 512, us = (i & 7) << 6;
                half8 u8[8];
                #pragma unroll
                for (int kt = 0; kt < 8; ++kt)
                    u8[kt] = *(const half8*)(Ub + ub + ((kt * 64 + kg16 + us) & 511));
                f32x4 acc0 = {0, 0, 0, 0}, acc1 = {0, 0, 0, 0};
                f32x4 acc2 = {0, 0, 0, 0}, acc3 = {0, 0, 0, 0};
                #pragma unroll
                for (int kt = 0; kt < 8; ++kt) {
                    half8 afA = prelu_h8(u8[kt] + VrA[kt], pm1h);
                    half8 afB = prelu_h8(u8[kt] + VrB[kt], pm1h);
                    acc0 = __builtin_amdgcn_mfma_f32_16x16x32_f16(afA, Bf0[kt], acc0, 0, 0, 0);
                    acc1 = __builtin_amdgcn_mfma_f32_16x16x32_f16(afA, Bf1[kt], acc1, 0, 0, 0);
                    acc2 = __builtin_amdgcn_mfma_f32_16x16x32_f16(afB, Bf0[kt], acc2, 0, 0, 0);
                    acc3 = __builtin_amdgcn_mfma_f32_16x16x32_f16(afB, Bf1[kt], acc3, 0, 0, 0);
                }
                #pragma unroll
                for (int r = 0; r < 4; ++r) {
                    psum += prelu_f(acc0[r] + bm2c0, pm2v) * ug0;
                    psum += prelu_f(acc1[r] + bm2c1, pm2v) * ug1;
                    psum += prelu_f(acc2[r] + bm2c0, pm2v) * ug0;
                    psum += prelu_f(acc3[r] + bm2c1, pm2v) * ug1;
                }
            }
        }
        #pragma unroll
        for (int m = 1; m < 64; m <<= 1) psum += __shfl_xor(psum, m);
        if (lane == 0) {
            red[w] = psum;
            __threadfence_block();
            __hip_atomic_fetch_add(&cnt2, 1, __ATOMIC_RELEASE, __HIP_MEMORY_SCOPE_WORKGROUP);
            if (w == 0) {
                while (__hip_atomic_load(&cnt2, __ATOMIC_ACQUIRE, __HIP_MEMORY_SCOPE_WORKGROUP) < 4)
                    __builtin_amdgcn_s_sleep(1);
                __threadfence_block();
                out[g] = red[0] + red[1] + red[2] + red[3] + 1024.f * cbias_s;
            }
        }
    }
}

// ---- K2: globally-sequential sweep expander. 2048 blocks x 256 threads. ---
// 16384 units of 16KB, unit index == linear output address. Grid-striding
// makes the whole device write one contiguous moving front (fill pattern).
// xi unit u (u<8192): g=u>>5, i=u&31; all 32 rows equal staged row i.
// xj unit (u>=8192): v=u-8192, g=v>>5; rows j=0..31 from staged 16KB tile.
// Same-value overlapping reads/writes are benign.
__global__ __launch_bounds__(256) void expand_sweep(float* __restrict__ out)
{
    const int t = threadIdx.x;
    float* obase = out + 256;
    for (int u = blockIdx.x; u < 16384; u += 2048) {
        if (u < 8192) {
            const int g = u >> 5;
            const int i = u & 31;
            const float* src = obase + (size_t)g * 131072 + (size_t)i * 4096;
            f32x4 v = *(const f32x4*)(src + (t & 31) * 4);
            float* dst = obase + (size_t)u * 4096;
            #pragma unroll
            for (int s = 0; s < 4; ++s)
                *(f32x4*)(dst + (s * 256 + t) * 4) = v;
        } else {
            const int vv = u - 8192;
            const int g = vv >> 5;
            const float* srct = obase + XJ_OFF + (size_t)g * 131072;
            float* dst = obase + XJ_OFF + (size_t)g * 131072
                       + (size_t)(vv & 31) * 4096;
            #pragma unroll
            for (int s = 0; s < 4; ++s) {
                const int idx4 = s * 256 + t;
                f32x4 v = *(const f32x4*)(srct + (idx4 >> 5) * 128 + (idx4 & 31) * 4);
                *(f32x4*)(dst + idx4 * 4) = v;
            }
        }
    }
}

extern "C" void kernel_launch(void* const* d_in, const int* in_sizes, int n_in,
                              void* d_out, int out_size, void* d_ws, size_t ws_size,
                              hipStream_t stream) {
    const float* x1   = (const float*)d_in[0];
    const float* x2   = (const float*)d_in[1];
    const float* itr  = (const float*)d_in[2];
    const float* a    = (const float*)d_in[8];
    const float* Wm1  = (const float*)d_in[9];
    const float* bm1  = (const float*)d_in[10];
    const float* Wm2  = (const float*)d_in[11];
    const float* bm2  = (const float*)d_in[12];
    const float* Wm3  = (const float*)d_in[13];
    const float* bm3  = (const float*)d_in[14];
    const float* pm0  = (const float*)d_in[15];
    const float* pm1  = (const float*)d_in[16];
    const float* pm2  = (const float*)d_in[17];
    const float* Wg1a = (const float*)d_in[18];
    const float* bg1a = (const float*)d_in[19];
    const float* Wg1b = (const float*)d_in[20];
    const float* bg1b = (const float*)d_in[21];
    const float* pw1  = (const float*)d_in[22];
    const float* Wg2a = (const float*)d_in[23];
    const float* bg2a = (const float*)d_in[24];
    const float* Wg2b = (const float*)d_in[25];
    const float* bg2b = (const float*)d_in[26];
    const float* pw2  = (const float*)d_in[27];
    float* out = (float*)d_out;
    short* Wt = (short*)d_ws;   // 320 KB

    hipLaunchKernelGGL(prep_weights, dim3(32), dim3(256), 0, stream,
                       Wm1, Wm2, Wg1a, Wg2a, Wt);
    hipLaunchKernelGGL(interactions_core, dim3(256), dim3(512), 0, stream,
                       x1, x2, itr, a, Wt, bm1, bm2, Wm3, bm3,
                       pm0, pm1, pm2, bg1a, Wg1b, bg1b, pw1,
                       bg2a, Wg2b, bg2b, pw2, out);
    hipLaunchKernelGGL(expand_sweep, dim3(2048), dim3(256), 0, stream, out);
}

// Round 13
// 82.764 us; speedup vs baseline: 1.4169x; 1.4169x over previous
//
#include <hip/hip_runtime.h>
#include <hip/hip_bf16.h>
#include <hip/hip_fp16.h>

typedef __attribute__((ext_vector_type(8))) _Float16 half8;
typedef __attribute__((ext_vector_type(2))) _Float16 f16x2;
typedef __attribute__((ext_vector_type(8))) short short8;
typedef __attribute__((ext_vector_type(4))) float f32x4;

#define C_ 128

__device__ __forceinline__ unsigned short f2h(float f) {
    return __builtin_bit_cast(unsigned short, (_Float16)f);
}
__device__ __forceinline__ f16x2 pkrtz(float x, float y) {
    return __builtin_bit_cast(f16x2, __builtin_amdgcn_cvt_pkrtz(x, y));
}
__device__ __forceinline__ float prelu_f(float x, float s) {
    return fmaxf(x, 0.f) + s * fminf(x, 0.f);
}
__device__ __forceinline__ half8 prelu_h8(half8 x, half8 sl) {
    half8 z = {0, 0, 0, 0, 0, 0, 0, 0};
    half8 mx = __builtin_elementwise_max(x, z);
    half8 mn = __builtin_elementwise_min(x, z);
    return mn * sl + mx;
}
// streaming store: system-coherent + nontemporal (bypass/evict-first in
// L2/MALL) — replicates runtime fill's write policy
__device__ __forceinline__ void store_stream(float* p, f32x4 v) {
    asm volatile("global_store_dwordx4 %0, %1, off sc0 sc1 nt"
                 :: "v"(p), "v"(v) : "memory");
}

// ---- K0: convert + transpose weights to f16 in d_ws ----
__global__ __launch_bounds__(256) void prep_weights(
    const float* __restrict__ Wm1, const float* __restrict__ Wm2,
    const float* __restrict__ Wg1a, const float* __restrict__ Wg2a,
    short* __restrict__ ws)
{
    int id = blockIdx.x * 256 + threadIdx.x;
    if (id < 8192) {
        int c = id >> 5, kb = (id & 31) * 8;
        short8 v;
        #pragma unroll
        for (int e = 0; e < 8; ++e) v[e] = (short)f2h(Wm1[(kb + e) * 256 + c]);
        *(short8*)(ws + c * 256 + kb) = v;
    }
    if (id < 4096) {
        int c = id >> 5, kb = (id & 31) * 8;
        short8 a, b, d;
        #pragma unroll
        for (int e = 0; e < 8; ++e) {
            a[e] = (short)f2h(Wm2 [(kb + e) * C_ + c]);
            b[e] = (short)f2h(Wg1a[(kb + e) * C_ + c]);
            d[e] = (short)f2h(Wg2a[(kb + e) * C_ + c]);
        }
        *(short8*)(ws + 65536  + c * 256 + kb) = a;
        *(short8*)(ws + 98304  + c * 256 + kb) = b;
        *(short8*)(ws + 131072 + c * 256 + kb) = d;
    }
}

// One block per graph. 512 threads = 8 waves.
// Waves 0-3: P4 U/V + P5 pair MFMA + logit, then join stores.
// Waves 4-7: ug/cbias, then store immediately.
// Stores: 64 dynamic units of 16 KB, work-stealing, streaming-policy stores.
__global__ __launch_bounds__(512, 1) void interactions_fused(
    const float* __restrict__ x1_, const float* __restrict__ x2_,
    const float* __restrict__ inter, const float* __restrict__ aP,
    const short* __restrict__ Wt,
    const float* __restrict__ bm1, const float* __restrict__ bm2,
    const float* __restrict__ Wm3, const float* __restrict__ bm3,
    const float* __restrict__ pm0p, const float* __restrict__ pm1p,
    const float* __restrict__ pm2p,
    const float* __restrict__ bg1a, const float* __restrict__ Wg1b,
    const float* __restrict__ bg1b, const float* __restrict__ pw1p,
    const float* __restrict__ bg2a, const float* __restrict__ Wg2b,
    const float* __restrict__ bg2b, const float* __restrict__ pw2p,
    float* __restrict__ out)
{
    __shared__ __align__(16) float xs1[32 * 132];
    __shared__ __align__(16) float xs2[32 * 132];
    __shared__ __align__(16) unsigned char Ub[16384];
    __shared__ __align__(16) unsigned char Vb[16384];
    __shared__ __align__(16) float rr[2][C_];
    __shared__ __align__(16) float tv[C_];
    __shared__ __align__(16) float ugs[C_];
    __shared__ float wgtp[2][2][32];
    __shared__ float red[4];
    __shared__ float cbias_s;
    __shared__ int cnt1, cnt2, ucnt;

    const int t = threadIdx.x;
    const int g = blockIdx.x;
    const int lane = t & 63;
    const int w = t >> 6;

    if (t == 0) { cnt1 = 0; cnt2 = 0; ucnt = 0; }

    // ---------------- P0: load x tiles ----------------
    {
        const float* s1 = x1_ + (size_t)g * 4096;
        const float* s2 = x2_ + (size_t)g * 4096;
        #pragma unroll
        for (int q = 0; q < 2; ++q) {
            int idx = q * 512 + t;
            int row = idx >> 5, cc = (idx & 31) * 4;
            f32x4 v1 = *(const f32x4*)(s1 + idx * 4);
            f32x4 v2 = *(const f32x4*)(s2 + idx * 4);
            *(f32x4*)(xs1 + row * 132 + cc) = v1;
            *(f32x4*)(xs2 + row * 132 + cc) = v2;
        }
    }
    __syncthreads();

    // ---------------- P1: readouts + tv ----------------
    if (t < 128) {
        float s = 0.f;
        for (int n = 0; n < 32; ++n) s += xs1[n * 132 + t];
        rr[0][t] = s;
    } else if (t < 256) {
        int c = t - 128;
        float s = 0.f;
        for (int n = 0; n < 32; ++n) s += xs2[n * 132 + c];
        rr[1][c] = s;
    } else if (t < 384) {
        int c = t - 256;
        tv[c] = aP[c] * inter[(size_t)g * C_ + c];
    }
    __syncthreads();

    // ---------------- P2: gating (f16 MFMA, 8 waves) ----------------
    {
        const int task = w & 3;
        const int half = w >> 2;
        const int sd = task >> 1;
        const int rt = task & 1;
        const float* xs = sd ? xs2 : xs1;
        const float* roth = sd ? rr[0] : rr[1];
        const short* WgT = Wt + (sd ? 131072 : 98304);
        const float* bga = sd ? bg2a : bg1a;
        const float* wgb = sd ? Wg2b : Wg1b;
        const float pw  = sd ? pw2p[0] : pw1p[0];
        const int row = rt * 16 + (lane & 15);
        const int kg = (lane >> 4) * 8;

        half8 afr[8];
        #pragma unroll
        for (int kt = 0; kt < 8; ++kt) {
            const float* p = (kt < 4) ? (xs + row * 132 + kt * 32 + kg)
                                      : (roth + (kt - 4) * 32 + kg);
            f32x4 lo = *(const f32x4*)p;
            f32x4 hi = *(const f32x4*)(p + 4);
            f16x2 a = pkrtz(lo[0], lo[1]);
            f16x2 b = pkrtz(lo[2], lo[3]);
            f16x2 c = pkrtz(hi[0], hi[1]);
            f16x2 d = pkrtz(hi[2], hi[3]);
            half8 fr = {a[0], a[1], b[0], b[1], c[0], c[1], d[0], d[1]};
            afr[kt] = fr;
        }
        float pr[4] = {0, 0, 0, 0};
        #pragma unroll
        for (int cq = 0; cq < 4; ++cq) {
            const int ct = half * 4 + cq;
            const int c = ct * 16 + (lane & 15);
            const short* wp = WgT + c * 256 + kg;
            f32x4 acc = {0, 0, 0, 0};
            #pragma unroll
            for (int kt = 0; kt < 8; ++kt)
                acc = __builtin_amdgcn_mfma_f32_16x16x32_f16(
                          afr[kt], *(const half8*)(wp + kt * 32), acc, 0, 0, 0);
            const float bgac = bga[c], wgbc = wgb[c];
            #pragma unroll
            for (int r = 0; r < 4; ++r)
                pr[r] += prelu_f(acc[r] + bgac, pw) * wgbc;
        }
        #pragma unroll
        for (int r = 0; r < 4; ++r) {
            float p = pr[r];
            p += __shfl_xor(p, 1); p += __shfl_xor(p, 2);
            p += __shfl_xor(p, 4); p += __shfl_xor(p, 8);
            if ((lane & 15) == 0)
                wgtp[half][sd][rt * 16 + (lane >> 4) * 4 + r] = p;
        }
    }
    __syncthreads();

    // ---------------- P3: sigmoid + scale xs in place ----------------
    {
        const float bgb1 = bg1b[0], bgb2 = bg2b[0];
        const int cc = (t & 31) * 4;
        const int tn = t >> 5;
        #pragma unroll
        for (int m = 0; m < 2; ++m) {
            const int nr = m * 16 + tn;
            const float w1v = 1.f / (1.f + __expf(-(wgtp[0][0][nr] + wgtp[1][0][nr] + bgb1)));
            const float w2v = 1.f / (1.f + __expf(-(wgtp[0][1][nr] + wgtp[1][1][nr] + bgb2)));
            f32x4 v1 = *(f32x4*)(xs1 + nr * 132 + cc);
            f32x4 v2 = *(f32x4*)(xs2 + nr * 132 + cc);
            v1 *= w1v; v2 *= w2v;
            *(f32x4*)(xs1 + nr * 132 + cc) = v1;
            *(f32x4*)(xs2 + nr * 132 + cc) = v2;
        }
    }
    __syncthreads();   // LAST full-block barrier

    if (w >= 4) {
        // ============ STORE-FIRST WAVES (4-7): ug/cbias then stores ========
        if (t < 384) {
            const int c = t - 256;
            const float* wr = Wm3 + c * C_;
            float s0 = 0, s1 = 0, s2 = 0, s3 = 0;
            #pragma unroll
            for (int k = 0; k < 128; k += 4) {
                f32x4 wv = *(const f32x4*)(wr + k);
                s0 += wv[0] * tv[k];     s1 += wv[1] * tv[k + 1];
                s2 += wv[2] * tv[k + 2]; s3 += wv[3] * tv[k + 3];
            }
            ugs[c] = (s0 + s1) + (s2 + s3);
        } else if (w == 7) {
            float p = bm3[lane] * tv[lane] + bm3[64 + lane] * tv[64 + lane];
            #pragma unroll
            for (int m = 1; m < 64; m <<= 1) p += __shfl_xor(p, m);
            if (lane == 0) cbias_s = p;
        }
        __threadfence_block();
        if (lane == 0)
            __hip_atomic_fetch_add(&cnt1, 1, __ATOMIC_RELEASE, __HIP_MEMORY_SCOPE_WORKGROUP);
    } else {
        // ============ COMPUTE WAVES (0-3) ============
        // P4: U/V via f16 MFMA into Ub/Vb (swizzled)
        {
            const int sd = w >> 1;
            const int rt = w & 1;
            const float* xs = sd ? xs2 : xs1;
            const float pm0 = pm0p[0];
            const int row = rt * 16 + (lane & 15);
            const int kg = (lane >> 4) * 8;
            half8 afr[4];
            #pragma unroll
            for (int kt = 0; kt < 4; ++kt) {
                const float* p = xs + row * 132 + kt * 32 + kg;
                f32x4 lo = *(const f32x4*)p;
                f32x4 hi = *(const f32x4*)(p + 4);
                f16x2 a = pkrtz(prelu_f(lo[0], pm0), prelu_f(lo[1], pm0));
                f16x2 b = pkrtz(prelu_f(lo[2], pm0), prelu_f(lo[3], pm0));
                f16x2 c = pkrtz(prelu_f(hi[0], pm0), prelu_f(hi[1], pm0));
                f16x2 d = pkrtz(prelu_f(hi[2], pm0), prelu_f(hi[3], pm0));
                half8 fr = {a[0], a[1], b[0], b[1], c[0], c[1], d[0], d[1]};
                afr[kt] = fr;
            }
            unsigned char* dst = sd ? Vb : Ub;
            #pragma unroll
            for (int ct = 0; ct < 16; ++ct) {
                const int c = ct * 16 + (lane & 15);
                const short* wp = Wt + c * 256 + sd * 128 + kg;
                f32x4 av = {0, 0, 0, 0};
                #pragma unroll
                for (int kt = 0; kt < 4; ++kt)
                    av = __builtin_amdgcn_mfma_f32_16x16x32_f16(
                             afr[kt], *(const half8*)(wp + kt * 32), av, 0, 0, 0);
                const float badd = sd ? 0.f : bm1[c];
                #pragma unroll
                for (int r = 0; r < 4; ++r) {
                    const int n = rt * 16 + (lane >> 4) * 4 + r;
                    const int off = n * 512 + ((2 * c + ((n & 7) << 6)) & 511);
                    *(unsigned short*)(dst + off) = f2h(av[r] + badd);
                }
            }
        }
        __threadfence_block();
        if (lane == 0)
            __hip_atomic_fetch_add(&cnt1, 1, __ATOMIC_RELEASE, __HIP_MEMORY_SCOPE_WORKGROUP);
        while (__hip_atomic_load(&cnt1, __ATOMIC_ACQUIRE, __HIP_MEMORY_SCOPE_WORKGROUP) < 8)
            __builtin_amdgcn_s_sleep(1);
        __threadfence_block();

        // P5: pair loop (no stores)
        float psum = 0.f;
        {
            const float pm1v = pm1p[0], pm2v = pm2p[0];
            const _Float16 pm1s = (_Float16)pm1v;
            const half8 pm1h = {pm1s, pm1s, pm1s, pm1s, pm1s, pm1s, pm1s, pm1s};
            const int cl = lane & 15;
            const int kg8 = (lane >> 4) * 8;
            const int kg16 = kg8 * 2;
            const int c0 = (2 * w) * 16 + cl, c1 = (2 * w + 1) * 16 + cl;
            half8 Bf0[8], Bf1[8];
            const short* w2p0 = Wt + 65536 + c0 * 256 + kg8;
            const short* w2p1 = Wt + 65536 + c1 * 256 + kg8;
            #pragma unroll
            for (int kt = 0; kt < 8; ++kt) {
                Bf0[kt] = *(const half8*)(w2p0 + kt * 32);
                Bf1[kt] = *(const half8*)(w2p1 + kt * 32);
            }
            const float bm2c0 = bm2[c0], bm2c1 = bm2[c1];
            const float ug0 = ugs[c0], ug1 = ugs[c1];

            half8 VrA[8], VrB[8];
            {
                const int j0 = cl, j1 = 16 + cl;
                #pragma unroll
                for (int kt = 0; kt < 8; ++kt) {
                    const int koff = kt * 64 + kg16;
                    VrA[kt] = *(const half8*)(Vb + j0 * 512 + ((koff + ((j0 & 7) << 6)) & 511));
                    VrB[kt] = *(const half8*)(Vb + j1 * 512 + ((koff + ((j1 & 7) << 6)) & 511));
                }
            }

            #pragma unroll 2
            for (int i = 0; i < 32; ++i) {
                const int ub = i * 512, us = (i & 7) << 6;
                half8 u8[8];
                #pragma unroll
                for (int kt = 0; kt < 8; ++kt)
                    u8[kt] = *(const half8*)(Ub + ub + ((kt * 64 + kg16 + us) & 511));
                f32x4 acc0 = {0, 0, 0, 0}, acc1 = {0, 0, 0, 0};
                f32x4 acc2 = {0, 0, 0, 0}, acc3 = {0, 0, 0, 0};
                #pragma unroll
                for (int kt = 0; kt < 8; ++kt) {
                    half8 afA = prelu_h8(u8[kt] + VrA[kt], pm1h);
                    half8 afB = prelu_h8(u8[kt] + VrB[kt], pm1h);
                    acc0 = __builtin_amdgcn_mfma_f32_16x16x32_f16(afA, Bf0[kt], acc0, 0, 0, 0);
                    acc1 = __builtin_amdgcn_mfma_f32_16x16x32_f16(afA, Bf1[kt], acc1, 0, 0, 0);
                    acc2 = __builtin_amdgcn_mfma_f32_16x16x32_f16(afB, Bf0[kt], acc2, 0, 0, 0);
                    acc3 = __builtin_amdgcn_mfma_f32_16x16x32_f16(afB, Bf1[kt], acc3, 0, 0, 0);
                }
                #pragma unroll
                for (int r = 0; r < 4; ++r) {
                    psum += prelu_f(acc0[r] + bm2c0, pm2v) * ug0;
                    psum += prelu_f(acc1[r] + bm2c1, pm2v) * ug1;
                    psum += prelu_f(acc2[r] + bm2c0, pm2v) * ug0;
                    psum += prelu_f(acc3[r] + bm2c1, pm2v) * ug1;
                }
            }
        }
        #pragma unroll
        for (int m = 1; m < 64; m <<= 1) psum += __shfl_xor(psum, m);
        if (lane == 0) {
            red[w] = psum;
            __threadfence_block();
            __hip_atomic_fetch_add(&cnt2, 1, __ATOMIC_RELEASE, __HIP_MEMORY_SCOPE_WORKGROUP);
            if (w == 0) {
                while (__hip_atomic_load(&cnt2, __ATOMIC_ACQUIRE, __HIP_MEMORY_SCOPE_WORKGROUP) < 4)
                    __builtin_amdgcn_s_sleep(1);
                __threadfence_block();
                out[g] = red[0] + red[1] + red[2] + red[3] + 1024.f * cbias_s;
            }
        }
    }

    // ============ COMMON: dynamic store loop (streaming-policy stores) =====
    {
        float* oxi = out + 256 + (size_t)g * 131072;
        float* oxj = out + 256 + 33554432 + (size_t)g * 131072;
        const int ccl = (lane & 31) * 4;

        // preload the xj 32-row tile pattern (identical for every xj unit)
        f32x4 vj[16];
        #pragma unroll
        for (int s2 = 0; s2 < 16; ++s2) {
            const int jn = 2 * s2 + (lane >> 5);
            vj[s2] = *(const f32x4*)(xs2 + jn * 132 + ccl);
        }

        for (;;) {
            int u = 0;
            if (lane == 0)
                u = __hip_atomic_fetch_add(&ucnt, 1, __ATOMIC_RELAXED,
                                           __HIP_MEMORY_SCOPE_WORKGROUP);
            u = __shfl(u, 0);
            if (u >= 64) break;
            if (u < 32) {
                // xi unit u: 32 rows, all equal x1g[u]
                f32x4 v = *(const f32x4*)(xs1 + u * 132 + ccl);
                float* base = oxi + u * 4096 + lane * 4;
                #pragma unroll
                for (int s2 = 0; s2 < 16; ++s2)
                    store_stream(base + s2 * 256, v);
            } else {
                // xj unit: rows (u-32)*32..+32 = full x2g tile
                float* bb = oxj + (size_t)(u - 32) * 4096 + lane * 4;
                #pragma unroll
                for (int s2 = 0; s2 < 16; ++s2)
                    store_stream(bb + s2 * 256, vj[s2]);
            }
        }
    }
}

extern "C" void kernel_launch(void* const* d_in, const int* in_sizes, int n_in,
                              void* d_out, int out_size, void* d_ws, size_t ws_size,
                              hipStream_t stream) {
    const float* x1   = (const float*)d_in[0];
    const float* x2   = (const float*)d_in[1];
    const float* itr  = (const float*)d_in[2];
    const float* a    = (const float*)d_in[8];
    const float* Wm1  = (const float*)d_in[9];
    const float* bm1  = (const float*)d_in[10];
    const float* Wm2  = (const float*)d_in[11];
    const float* bm2  = (const float*)d_in[12];
    const float* Wm3  = (const float*)d_in[13];
    const float* bm3  = (const float*)d_in[14];
    const float* pm0  = (const float*)d_in[15];
    const float* pm1  = (const float*)d_in[16];
    const float* pm2  = (const float*)d_in[17];
    const float* Wg1a = (const float*)d_in[18];
    const float* bg1a = (const float*)d_in[19];
    const float* Wg1b = (const float*)d_in[20];
    const float* bg1b = (const float*)d_in[21];
    const float* pw1  = (const float*)d_in[22];
    const float* Wg2a = (const float*)d_in[23];
    const float* bg2a = (const float*)d_in[24];
    const float* Wg2b = (const float*)d_in[25];
    const float* bg2b = (const float*)d_in[26];
    const float* pw2  = (const float*)d_in[27];
    float* out = (float*)d_out;
    short* Wt = (short*)d_ws;   // 320 KB

    hipLaunchKernelGGL(prep_weights, dim3(32), dim3(256), 0, stream,
                       Wm1, Wm2, Wg1a, Wg2a, Wt);
    hipLaunchKernelGGL(interactions_fused, dim3(256), dim3(512), 0, stream,
                       x1, x2, itr, a, Wt, bm1, bm2, Wm3, bm3,
                       pm0, pm1, pm2, bg1a, Wg1b, bg1b, pw1,
                       bg2a, Wg2b, bg2b, pw2, out);
}